// Round 1
// baseline (482.727 us; speedup 1.0000x reference)
//
#include <hip/hip_runtime.h>

// DCT-II orthonormal basis D[x][u] = alpha[u] * cos(pi*u*(2x+1)/16),
// alpha[0]=sqrt(1/8), alpha[u>0]=0.5. Compile-time constants -> folded to
// literals/SGPRs, no global loads.
__device__ __constant__ static const float kD[8][8] = {
  { 0.3535533906f,  0.4903926402f,  0.4619397663f,  0.4157348062f,  0.3535533906f,  0.2777851165f,  0.1913417162f,  0.0975451610f},
  { 0.3535533906f,  0.4157348062f,  0.1913417162f, -0.0975451610f, -0.3535533906f, -0.4903926402f, -0.4619397663f, -0.2777851165f},
  { 0.3535533906f,  0.2777851165f, -0.1913417162f, -0.4903926402f, -0.3535533906f,  0.0975451610f,  0.4619397663f,  0.4157348062f},
  { 0.3535533906f,  0.0975451610f, -0.4619397663f, -0.2777851165f,  0.3535533906f,  0.4157348062f, -0.1913417162f, -0.4903926402f},
  { 0.3535533906f, -0.0975451610f, -0.4619397663f,  0.2777851165f,  0.3535533906f, -0.4157348062f, -0.1913417162f,  0.4903926402f},
  { 0.3535533906f, -0.2777851165f, -0.1913417162f,  0.4903926402f, -0.3535533906f, -0.0975451610f,  0.4619397663f, -0.4157348062f},
  { 0.3535533906f, -0.4157348062f,  0.1913417162f,  0.0975451610f, -0.3535533906f,  0.4903926402f, -0.4619397663f,  0.2777851165f},
  { 0.3535533906f, -0.4903926402f,  0.4619397663f, -0.4157348062f,  0.3535533906f, -0.2777851165f,  0.1913417162f, -0.0975451610f},
};

#define NPLANES   96            // 32 * 3
#define IMG_W     512
#define PLANE_SZ  (512 * 512)
#define NBLOCKS   (NPLANES * 64 * 64)   // 393216 8x8 blocks

__global__ __launch_bounds__(256) void dct_corners_kernel(
    const float* __restrict__ x, float* __restrict__ out) {
  const int g = blockIdx.x * 256 + threadIdx.x;
  if (g >= NBLOCKS) return;

  const int p   = g >> 12;        // plane index (4096 blocks per 512x512 plane)
  const int blk = g & 4095;
  const int by  = blk >> 6;
  const int bx  = blk & 63;       // consecutive threads -> consecutive bx (coalesced)

  const size_t base = (size_t)p * PLANE_SZ + (size_t)(by * 8) * IMG_W + (size_t)(bx * 8);
  const float* src = x + base;

  // ---- load 8x8 block (2x float4 per row; 16B aligned, 32B thread stride) ----
  float s[8][8];
#pragma unroll
  for (int r = 0; r < 8; ++r) {
    const float4 a = *reinterpret_cast<const float4*>(src + r * IMG_W);
    const float4 b = *reinterpret_cast<const float4*>(src + r * IMG_W + 4);
    s[r][0] = a.x; s[r][1] = a.y; s[r][2] = a.z; s[r][3] = a.w;
    s[r][4] = b.x; s[r][5] = b.y; s[r][6] = b.z; s[r][7] = b.w;
  }

  // ---- vertical DCT: V[u][j] = sum_r D[r][u] * s[r][j] ----
  float V[8][8];
#pragma unroll
  for (int u = 0; u < 8; ++u) {
#pragma unroll
    for (int j = 0; j < 8; ++j) {
      float acc = 0.0f;
#pragma unroll
      for (int r = 0; r < 8; ++r) acc = fmaf(kD[r][u], s[r][j], acc);
      V[u][j] = acc;
    }
  }

  // ---- horizontal DCT: C[k][l] = sum_j V[k][j] * D[j][l] ----
  float C[8][8];
#pragma unroll
  for (int k = 0; k < 8; ++k) {
#pragma unroll
    for (int l = 0; l < 8; ++l) {
      float acc = 0.0f;
#pragma unroll
      for (int j = 0; j < 8; ++j) acc = fmaf(V[k][j], kD[j][l], acc);
      C[k][l] = acc;
    }
  }

  // ---- partial inverse along l: masks are separable, corners share these ----
  // TL[k][j] = sum_{l<4} C[k][l]*D[j][l]   (left  column-mask half)
  // TH[k][j] = sum_{l>=4} C[k][l]*D[j][l]  (right column-mask half)
  float TL[8][8], TH[8][8];
#pragma unroll
  for (int k = 0; k < 8; ++k) {     // per-k so C[k][*] dies as we go (reg pressure)
#pragma unroll
    for (int j = 0; j < 8; ++j) {
      float al = 0.0f, ah = 0.0f;
#pragma unroll
      for (int l = 0; l < 4; ++l) {
        al = fmaf(C[k][l],     kD[j][l],     al);
        ah = fmaf(C[k][l + 4], kD[j][l + 4], ah);
      }
      TL[k][j] = al;
      TH[k][j] = ah;
    }
  }

  // ---- inverse along k per corner, store row-by-row ----
  // corner0: k<4, l<4 (TL) | corner1: k<4, l>=4 (TH)
  // corner2: k>=4, TL      | corner3: k>=4, TH
  const size_t corner_stride = (size_t)NPLANES * PLANE_SZ;
  float* o = out + base;
#pragma unroll
  for (int i = 0; i < 8; ++i) {
    float r0[8], r1[8], r2[8], r3[8];
#pragma unroll
    for (int j = 0; j < 8; ++j) {
      float a0 = 0.0f, a1 = 0.0f, a2 = 0.0f, a3 = 0.0f;
#pragma unroll
      for (int k = 0; k < 4; ++k) {
        const float dl = kD[i][k];
        const float dh = kD[i][k + 4];
        a0 = fmaf(dl, TL[k][j],     a0);
        a1 = fmaf(dl, TH[k][j],     a1);
        a2 = fmaf(dh, TL[k + 4][j], a2);
        a3 = fmaf(dh, TH[k + 4][j], a3);
      }
      r0[j] = a0; r1[j] = a1; r2[j] = a2; r3[j] = a3;
    }
    float* row = o + (size_t)i * IMG_W;
    *reinterpret_cast<float4*>(row)                         = make_float4(r0[0], r0[1], r0[2], r0[3]);
    *reinterpret_cast<float4*>(row + 4)                     = make_float4(r0[4], r0[5], r0[6], r0[7]);
    *reinterpret_cast<float4*>(row + corner_stride)         = make_float4(r1[0], r1[1], r1[2], r1[3]);
    *reinterpret_cast<float4*>(row + corner_stride + 4)     = make_float4(r1[4], r1[5], r1[6], r1[7]);
    *reinterpret_cast<float4*>(row + 2 * corner_stride)     = make_float4(r2[0], r2[1], r2[2], r2[3]);
    *reinterpret_cast<float4*>(row + 2 * corner_stride + 4) = make_float4(r2[4], r2[5], r2[6], r2[7]);
    *reinterpret_cast<float4*>(row + 3 * corner_stride)     = make_float4(r3[0], r3[1], r3[2], r3[3]);
    *reinterpret_cast<float4*>(row + 3 * corner_stride + 4) = make_float4(r3[4], r3[5], r3[6], r3[7]);
  }
}

extern "C" void kernel_launch(void* const* d_in, const int* in_sizes, int n_in,
                              void* d_out, int out_size, void* d_ws, size_t ws_size,
                              hipStream_t stream) {
  const float* x = (const float*)d_in[0];
  float* out = (float*)d_out;
  const int threads = 256;
  const int grid = (NBLOCKS + threads - 1) / threads;   // 1536
  hipLaunchKernelGGL(dct_corners_kernel, dim3(grid), dim3(threads), 0, stream, x, out);
}